// Round 1
// baseline (1146.887 us; speedup 1.0000x reference)
//
#include <hip/hip_runtime.h>
#include <math.h>

// Mask R-CNN cascade head, fp32 baseline.
// Pipeline per stage: roi-align pool -> FC1(12544x1024)+ReLU -> FC2(1024x1024)+ReLU
//                     -> cls(1024x81) / loc(1024x324) -> decode (softmax/argmax/bbox)
// Sequential dependency across stages via roi buffer in ws.

#define NROI 256
#define NCLS 80

// ---------------- init: copy rois into ws, valid=1 ----------------
__global__ __launch_bounds__(256) void init_kernel(const float* __restrict__ rois,
                                                   float* __restrict__ roi,
                                                   float* __restrict__ valid) {
  int i = blockIdx.x * 256 + threadIdx.x;
  if (i < NROI * 4) roi[i] = rois[i];
  if (i < NROI) valid[i] = 1.0f;
}

// ---------------- ROI align pool: pooled[n][c][7][7] ----------------
// grid: 12544 blocks x 256 threads; each block is entirely within one roi
// (12544 elements per roi / 256 = 49 blocks per roi) -> uniform level, no divergence.
__global__ __launch_bounds__(256) void pool_kernel(
    const float* __restrict__ P0, const float* __restrict__ P1,
    const float* __restrict__ P2, const float* __restrict__ P3,
    const float* __restrict__ roi, float* __restrict__ pooled) {
  int idx = blockIdx.x * 256 + threadIdx.x;
  int px = idx % 7;
  int py = (idx / 7) % 7;
  int c  = (idx / 49) % 256;
  int n  = idx / 12544;

  float r0 = roi[n * 4 + 0];
  float r1 = roi[n * 4 + 1];
  float r2 = roi[n * 4 + 2];
  float r3 = roi[n * 4 + 3];

  // FPN level assignment
  float area = (r2 - r0 + 1.0f) * (r3 - r1 + 1.0f);
  float lf = floorf(4.0f + log2f(sqrtf(area) / 224.0f));
  lf = fminf(fmaxf(lf, 2.0f), 5.0f);
  int lvl = (int)lf - 2;

  float scale;
  int H;
  const float* feat;
  if (lvl == 0)      { scale = 0.25f;    H = 256; feat = P0; }
  else if (lvl == 1) { scale = 0.125f;   H = 128; feat = P1; }
  else if (lvl == 2) { scale = 0.0625f;  H = 64;  feat = P2; }
  else               { scale = 0.03125f; H = 32;  feat = P3; }
  int W = H;

  float y1 = r0 * scale;
  float x1 = r1 * scale;
  float rh = fmaxf(r2 * scale - y1, 1.0f);
  float rw = fmaxf(r3 * scale - x1, 1.0f);
  float bh = rh * (1.0f / 7.0f);
  float bw = rw * (1.0f / 7.0f);

  const float* fc = feat + (size_t)c * H * W;
  float sum = 0.0f;
#pragma unroll
  for (int ry = 0; ry < 2; ry++) {
    float yy = y1 + ((float)py + ((float)ry + 0.5f) * 0.5f) * bh;
    bool vy = (yy > -1.0f) && (yy < (float)H);
    float yc = fminf(fmaxf(yy, 0.0f), (float)(H - 1));
    float y0f = floorf(yc);
    float ly = yc - y0f;
    int y0i = (int)y0f;
    int y1i = min(y0i + 1, H - 1);
#pragma unroll
    for (int rx = 0; rx < 2; rx++) {
      float xx = x1 + ((float)px + ((float)rx + 0.5f) * 0.5f) * bw;
      bool vx = (xx > -1.0f) && (xx < (float)W);
      float xc = fminf(fmaxf(xx, 0.0f), (float)(W - 1));
      float x0f = floorf(xc);
      float lx = xc - x0f;
      int x0i = (int)x0f;
      int x1i = min(x0i + 1, W - 1);
      float f00 = fc[y0i * W + x0i];
      float f01 = fc[y0i * W + x1i];
      float f10 = fc[y1i * W + x0i];
      float f11 = fc[y1i * W + x1i];
      float v = f00 * (1.0f - ly) * (1.0f - lx) + f01 * (1.0f - ly) * lx +
                f10 * ly * (1.0f - lx) + f11 * ly * lx;
      sum += (vy && vx) ? v : 0.0f;
    }
  }
  pooled[idx] = sum * 0.25f;
}

// ---------------- tiled SGEMM, 64x64 tile, 4x4 per thread, split-K atomic ----------------
// A: (M,K) row-major, B: (K,N) row-major, C: (M,N) pre-zeroed, C += A@B.
__global__ __launch_bounds__(256) void gemm_atomic(
    const float* __restrict__ A, const float* __restrict__ B,
    float* __restrict__ C, int M, int N, int K, int kChunk) {
  __shared__ float As[16][68];  // [k][m], padded row=68 floats (16B-aligned, bank-shift 4)
  __shared__ float Bs[16][64];  // [k][n]
  const int tid = threadIdx.x;
  const int m0 = blockIdx.y * 64;
  const int n0 = blockIdx.x * 64;
  const int k0 = blockIdx.z * kChunk;
  const int tx = tid & 15;
  const int ty = tid >> 4;
  const int am = tid >> 2;         // 0..63
  const int ak = (tid & 3) << 2;   // 0,4,8,12
  const bool vec = ((N & 3) == 0) && (n0 + 64 <= N);

  float acc[4][4];
#pragma unroll
  for (int i = 0; i < 4; i++)
#pragma unroll
    for (int j = 0; j < 4; j++) acc[i][j] = 0.0f;

  for (int kt = k0; kt < k0 + kChunk; kt += 16) {
    // A tile 64x16 -> As transposed [k][m]
    float4 av = *(const float4*)(A + (size_t)(m0 + am) * K + (kt + ak));
    As[ak + 0][am] = av.x;
    As[ak + 1][am] = av.y;
    As[ak + 2][am] = av.z;
    As[ak + 3][am] = av.w;
    // B tile 16x64
    if (vec) {
      const int br = ty;               // 0..15
      const int bc4 = tx << 2;         // 0..60
      *(float4*)(&Bs[br][bc4]) =
          *(const float4*)(B + (size_t)(kt + br) * N + (n0 + bc4));
    } else {
#pragma unroll
      for (int i = 0; i < 4; i++) {
        int e = i * 256 + tid;
        int br = e >> 6, bcc = e & 63;
        int col = n0 + bcc;
        Bs[br][bcc] = (col < N) ? B[(size_t)(kt + br) * N + col] : 0.0f;
      }
    }
    __syncthreads();
#pragma unroll
    for (int kk = 0; kk < 16; kk++) {
      float4 a = *(const float4*)(&As[kk][ty << 2]);
      float4 b = *(const float4*)(&Bs[kk][tx << 2]);
      acc[0][0] += a.x * b.x; acc[0][1] += a.x * b.y; acc[0][2] += a.x * b.z; acc[0][3] += a.x * b.w;
      acc[1][0] += a.y * b.x; acc[1][1] += a.y * b.y; acc[1][2] += a.y * b.z; acc[1][3] += a.y * b.w;
      acc[2][0] += a.z * b.x; acc[2][1] += a.z * b.y; acc[2][2] += a.z * b.z; acc[2][3] += a.z * b.w;
      acc[3][0] += a.w * b.x; acc[3][1] += a.w * b.y; acc[3][2] += a.w * b.z; acc[3][3] += a.w * b.w;
    }
    __syncthreads();
  }
#pragma unroll
  for (int i = 0; i < 4; i++) {
    int row = m0 + (ty << 2) + i;
#pragma unroll
    for (int j = 0; j < 4; j++) {
      int col = n0 + (tx << 2) + j;
      if (col < N) atomicAdd(&C[(size_t)row * N + col], acc[i][j]);
    }
  }
}

// ---------------- bias + relu (1024 features) ----------------
__global__ __launch_bounds__(256) void bias_relu(float* __restrict__ h,
                                                 const float* __restrict__ b,
                                                 int total) {
  int i = blockIdx.x * 256 + threadIdx.x;
  if (i < total) {
    float v = h[i] + b[i & 1023];
    h[i] = fmaxf(v, 0.0f);
  }
}

// ---------------- decode: softmax, bbox decode, accumulate, argmax -> new roi ----------------
__global__ __launch_bounds__(128) void decode_kernel(
    const float* __restrict__ logits, const float* __restrict__ bc,
    const float* __restrict__ locr, const float* __restrict__ bl,
    float* __restrict__ roi, float* __restrict__ valid,
    float* __restrict__ pre_b, float* __restrict__ pre_s,
    float st0, float st1, float st2, float st3, int stage) {
  int n = blockIdx.x;
  int t = threadIdx.x;
  __shared__ float red[128];
  __shared__ int redi[128];
  __shared__ float sroi[4];
  __shared__ float boxes[NCLS][4];

  if (t < 4) sroi[t] = roi[n * 4 + t];
  float l = (t < 81) ? (logits[n * 81 + t] + bc[t]) : -INFINITY;
  red[t] = l;
  __syncthreads();
#pragma unroll
  for (int s = 64; s > 0; s >>= 1) {
    if (t < s) red[t] = fmaxf(red[t], red[t + s]);
    __syncthreads();
  }
  float mx = red[0];
  __syncthreads();
  red[t] = (t < 81) ? expf(l - mx) : 0.0f;
  __syncthreads();
#pragma unroll
  for (int s = 64; s > 0; s >>= 1) {
    if (t < s) red[t] += red[t + s];
    __syncthreads();
  }
  float denom = red[0];
  __syncthreads();

  float score = -INFINITY;
  if (t < NCLS) {
    // class t corresponds to logit/loc index t+1
    float lj = logits[n * 81 + t + 1] + bc[t + 1];
    score = expf(lj - mx) / denom;
    const float* lp = locr + (size_t)n * 324 + (t + 1) * 4;
    const float* bp = bl + (t + 1) * 4;
    float dy = (lp[0] + bp[0]) * st0;
    float dx = (lp[1] + bp[1]) * st1;
    float dh = (lp[2] + bp[2]) * st2;
    float dw = (lp[3] + bp[3]) * st3;
    float h_ = sroi[2] - sroi[0];
    float w_ = sroi[3] - sroi[1];
    float cy = sroi[0] + h_ * 0.5f;
    float cx = sroi[1] + w_ * 0.5f;
    float ny = dy * h_ + cy;
    float nx = dx * w_ + cx;
    float nh = expf(dh) * h_;
    float nw = expf(dw) * w_;
    float b0 = ny - nh * 0.5f;
    float b1v = nx - nw * 0.5f;
    float b2v = ny + nh * 0.5f;
    float b3v = nx + nw * 0.5f;
    int o = (n * NCLS + t) * 4;
    pre_b[o + 0] += b0;
    pre_b[o + 1] += b1v;
    pre_b[o + 2] += b2v;
    pre_b[o + 3] += b3v;
    pre_s[n * NCLS + t] += score;
    boxes[t][0] = b0;
    boxes[t][1] = b1v;
    boxes[t][2] = b2v;
    boxes[t][3] = b3v;
  }
  red[t] = score;
  redi[t] = t;
  __syncthreads();
  for (int s = 64; s > 0; s >>= 1) {
    if (t < s) {
      float o2 = red[t + s];
      int oi = redi[t + s];
      // jnp.argmax: first max index wins ties
      if (o2 > red[t] || (o2 == red[t] && oi < redi[t])) {
        red[t] = o2;
        redi[t] = oi;
      }
    }
    __syncthreads();
  }
  if (t == 0) {
    int best = redi[0];
    float ry1 = fminf(fmaxf(boxes[best][0], 0.0f), 1024.0f);
    float rx1 = fminf(fmaxf(boxes[best][1], 0.0f), 1024.0f);
    float ry2 = fminf(fmaxf(boxes[best][2], 0.0f), 1024.0f);
    float rx2 = fminf(fmaxf(boxes[best][3], 0.0f), 1024.0f);
    roi[n * 4 + 0] = ry1;
    roi[n * 4 + 1] = rx1;
    roi[n * 4 + 2] = ry2;
    roi[n * 4 + 3] = rx2;
    if (stage < 2) {
      float hh = ry2 - ry1, ww = rx2 - rx1;
      if (!(hh >= 16.0f && ww >= 16.0f)) valid[n] = 0.0f;
    }
  }
}

// ---------------- finalize: apply valid mask and /3, write output ----------------
__global__ __launch_bounds__(256) void finalize_kernel(
    const float* __restrict__ pre_b, const float* __restrict__ pre_s,
    const float* __restrict__ valid, float* __restrict__ out) {
  int i = blockIdx.x * 256 + threadIdx.x;
  if (i < NROI * NCLS * 4) {
    int n = i / (NCLS * 4);
    out[i] = pre_b[i] * valid[n] * (1.0f / 3.0f);
  } else if (i < NROI * NCLS * 4 + NROI * NCLS) {
    int j = i - NROI * NCLS * 4;
    int n = j / NCLS;
    out[i] = pre_s[j] * valid[n] * (1.0f / 3.0f);
  }
}

extern "C" void kernel_launch(void* const* d_in, const int* in_sizes, int n_in,
                              void* d_out, int out_size, void* d_ws, size_t ws_size,
                              hipStream_t stream) {
  const float* P0 = (const float*)d_in[0];
  const float* P1 = (const float*)d_in[1];
  const float* P2 = (const float*)d_in[2];
  const float* P3 = (const float*)d_in[3];
  const float* rois = (const float*)d_in[4];
  float* out = (float*)d_out;
  float* ws = (float*)d_ws;

  // ws layout (floats)
  float* roi    = ws;              // 1024
  float* valid  = ws + 1024;       // 256
  float* pre_b  = ws + 1280;       // 81920
  float* pre_s  = ws + 83200;      // 20480
  float* pooled = ws + 103680;     // 256*12544 = 3211264
  float* h1     = ws + 3314944;    // 262144
  float* h2     = ws + 3577088;    // 262144
  float* logit  = ws + 3839232;    // 20736
  float* loc    = ws + 3859968;    // 82944  -> total 3942912 floats = 15.8 MB

  init_kernel<<<4, 256, 0, stream>>>(rois, roi, valid);
  hipMemsetAsync(pre_b, 0, (size_t)(81920 + 20480) * sizeof(float), stream);

  const float stds[3][4] = {
      {0.1f, 0.1f, 0.2f, 0.2f},
      {0.05f, 0.05f, 0.1f, 0.1f},
      {1.0f / 30.0f, 1.0f / 30.0f, 1.0f / 15.0f, 1.0f / 15.0f}};

  for (int s = 0; s < 3; s++) {
    const float* W1 = (const float*)d_in[5 + s * 8 + 0];
    const float* b1 = (const float*)d_in[5 + s * 8 + 1];
    const float* W2 = (const float*)d_in[5 + s * 8 + 2];
    const float* b2 = (const float*)d_in[5 + s * 8 + 3];
    const float* Wc = (const float*)d_in[5 + s * 8 + 4];
    const float* bc = (const float*)d_in[5 + s * 8 + 5];
    const float* Wl = (const float*)d_in[5 + s * 8 + 6];
    const float* bl = (const float*)d_in[5 + s * 8 + 7];

    // zero GEMM accumulators (h1,h2,logit,loc contiguous)
    hipMemsetAsync(h1, 0, (size_t)(262144 + 262144 + 20736 + 82944) * sizeof(float), stream);

    pool_kernel<<<12544, 256, 0, stream>>>(P0, P1, P2, P3, roi, pooled);

    // FC1: (256 x 12544) @ (12544 x 1024), split-K 8 (chunk 1568)
    gemm_atomic<<<dim3(16, 4, 8), 256, 0, stream>>>(pooled, W1, h1, 256, 1024, 12544, 1568);
    bias_relu<<<1024, 256, 0, stream>>>(h1, b1, 262144);

    // FC2: (256 x 1024) @ (1024 x 1024), split-K 4
    gemm_atomic<<<dim3(16, 4, 4), 256, 0, stream>>>(h1, W2, h2, 256, 1024, 1024, 256);
    bias_relu<<<1024, 256, 0, stream>>>(h2, b2, 262144);

    // cls: (256 x 1024) @ (1024 x 81)
    gemm_atomic<<<dim3(2, 4, 4), 256, 0, stream>>>(h2, Wc, logit, 256, 81, 1024, 256);
    // loc: (256 x 1024) @ (1024 x 324)
    gemm_atomic<<<dim3(6, 4, 4), 256, 0, stream>>>(h2, Wl, loc, 256, 324, 1024, 256);

    decode_kernel<<<256, 128, 0, stream>>>(logit, bc, loc, bl, roi, valid, pre_b, pre_s,
                                           stds[s][0], stds[s][1], stds[s][2], stds[s][3], s);
  }

  finalize_kernel<<<400, 256, 0, stream>>>(pre_b, pre_s, valid, out);
}

// Round 2
// 733.029 us; speedup vs baseline: 1.5646x; 1.5646x over previous
//
#include <hip/hip_runtime.h>
#include <math.h>

// Mask R-CNN cascade head. FC1/FC2 use bf16 MFMA (16x16x32), cls/loc stay fp32.

#define NROI 256
#define NCLS 80
#define APITCH 40  // 32 k + 8 pad (bf16 elems); 80B row pitch keeps 16B alignment

typedef __attribute__((ext_vector_type(8))) short short8;
typedef __attribute__((ext_vector_type(4))) float f32x4;

__device__ __forceinline__ unsigned short f2bf(float f) {
  unsigned u = __builtin_bit_cast(unsigned, f);
  unsigned r = (u + 0x7FFFu + ((u >> 16) & 1u)) >> 16;  // RNE
  return (unsigned short)r;
}

// ---------------- init: copy rois into ws, valid=1 ----------------
__global__ __launch_bounds__(256) void init_kernel(const float* __restrict__ rois,
                                                   float* __restrict__ roi,
                                                   float* __restrict__ valid) {
  int i = blockIdx.x * 256 + threadIdx.x;
  if (i < NROI * 4) roi[i] = rois[i];
  if (i < NROI) valid[i] = 1.0f;
}

// ---------------- transpose + fp32->bf16: W (K,N) -> Wt (N,K) ----------------
// grid (K/32, N/32), block 256
__global__ __launch_bounds__(256) void transpose_bf16(const float* __restrict__ W,
                                                      unsigned short* __restrict__ Wt,
                                                      int K, int N) {
  __shared__ unsigned short tile[32][33];
  int t = threadIdx.x;
  int k0 = blockIdx.x * 32;
  int n0 = blockIdx.y * 32;
  int r = t >> 3;
  int c4 = (t & 7) * 4;
  float4 v = *(const float4*)(W + (size_t)(k0 + r) * N + n0 + c4);
  tile[r][c4 + 0] = f2bf(v.x);
  tile[r][c4 + 1] = f2bf(v.y);
  tile[r][c4 + 2] = f2bf(v.z);
  tile[r][c4 + 3] = f2bf(v.w);
  __syncthreads();
  // out element (n0+r, k0+c4+j) = tile[c4+j][r]
  struct __attribute__((aligned(8))) US4 { unsigned short a, b, c, d; } o;
  o.a = tile[c4 + 0][r];
  o.b = tile[c4 + 1][r];
  o.c = tile[c4 + 2][r];
  o.d = tile[c4 + 3][r];
  *(US4*)(Wt + (size_t)(n0 + r) * K + k0 + c4) = o;
}

// ---------------- ROI align pool -> bf16 pooled[n][c][7][7] ----------------
__global__ __launch_bounds__(256) void pool_kernel(
    const float* __restrict__ P0, const float* __restrict__ P1,
    const float* __restrict__ P2, const float* __restrict__ P3,
    const float* __restrict__ roi, unsigned short* __restrict__ pooled) {
  int idx = blockIdx.x * 256 + threadIdx.x;
  int px = idx % 7;
  int py = (idx / 7) % 7;
  int c  = (idx / 49) % 256;
  int n  = idx / 12544;

  float r0 = roi[n * 4 + 0];
  float r1 = roi[n * 4 + 1];
  float r2 = roi[n * 4 + 2];
  float r3 = roi[n * 4 + 3];

  float area = (r2 - r0 + 1.0f) * (r3 - r1 + 1.0f);
  float lf = floorf(4.0f + log2f(sqrtf(area) / 224.0f));
  lf = fminf(fmaxf(lf, 2.0f), 5.0f);
  int lvl = (int)lf - 2;

  float scale;
  int H;
  const float* feat;
  if (lvl == 0)      { scale = 0.25f;    H = 256; feat = P0; }
  else if (lvl == 1) { scale = 0.125f;   H = 128; feat = P1; }
  else if (lvl == 2) { scale = 0.0625f;  H = 64;  feat = P2; }
  else               { scale = 0.03125f; H = 32;  feat = P3; }
  int W = H;

  float y1 = r0 * scale;
  float x1 = r1 * scale;
  float rh = fmaxf(r2 * scale - y1, 1.0f);
  float rw = fmaxf(r3 * scale - x1, 1.0f);
  float bh = rh * (1.0f / 7.0f);
  float bw = rw * (1.0f / 7.0f);

  const float* fc = feat + (size_t)c * H * W;
  float sum = 0.0f;
#pragma unroll
  for (int ry = 0; ry < 2; ry++) {
    float yy = y1 + ((float)py + ((float)ry + 0.5f) * 0.5f) * bh;
    bool vy = (yy > -1.0f) && (yy < (float)H);
    float yc = fminf(fmaxf(yy, 0.0f), (float)(H - 1));
    float y0f = floorf(yc);
    float ly = yc - y0f;
    int y0i = (int)y0f;
    int y1i = min(y0i + 1, H - 1);
#pragma unroll
    for (int rx = 0; rx < 2; rx++) {
      float xx = x1 + ((float)px + ((float)rx + 0.5f) * 0.5f) * bw;
      bool vx = (xx > -1.0f) && (xx < (float)W);
      float xc = fminf(fmaxf(xx, 0.0f), (float)(W - 1));
      float x0f = floorf(xc);
      float lx = xc - x0f;
      int x0i = (int)x0f;
      int x1i = min(x0i + 1, W - 1);
      float f00 = fc[y0i * W + x0i];
      float f01 = fc[y0i * W + x1i];
      float f10 = fc[y1i * W + x0i];
      float f11 = fc[y1i * W + x1i];
      float v = f00 * (1.0f - ly) * (1.0f - lx) + f01 * (1.0f - ly) * lx +
                f10 * ly * (1.0f - lx) + f11 * ly * lx;
      sum += (vy && vx) ? v : 0.0f;
    }
  }
  pooled[idx] = f2bf(sum * 0.25f);
}

// ---------------- bf16 MFMA GEMM: C = A(MxK) @ Bt(NxK)^T, split-K partials ---------
// A, Bt both k-contiguous bf16. 128x128 tile, 4 waves (64x64 each), BK=32.
// grid (N/128, M/128, ksplit); each z writes its own partial buffer (no atomics).
__global__ __launch_bounds__(256) void gemm_bf16(
    const unsigned short* __restrict__ A, const unsigned short* __restrict__ B,
    float* __restrict__ Cpart, int M, int N, int K, int iters) {
  __shared__ unsigned short As[128 * APITCH];
  __shared__ unsigned short Bs[128 * APITCH];
  const int t = threadIdx.x;
  const int n0 = blockIdx.x * 128;
  const int m0 = blockIdx.y * 128;
  const size_t kt0 = (size_t)blockIdx.z * iters * 32;

  // staging: thread loads 16B for rows (row, row+64) at k-offset off
  const int row = t >> 2;
  const int off = (t & 3) * 8;
  const unsigned short* pa0 = A + (size_t)(m0 + row) * K + kt0 + off;
  const unsigned short* pa1 = pa0 + (size_t)64 * K;
  const unsigned short* pb0 = B + (size_t)(n0 + row) * K + kt0 + off;
  const unsigned short* pb1 = pb0 + (size_t)64 * K;

  const int lane = t & 63;
  const int wave = t >> 6;
  const int wm = (wave >> 1) * 64;
  const int wn = (wave & 1) * 64;
  const int fr = lane & 15;
  const int kq = (lane >> 4) * 8;

  f32x4 acc[4][4];
#pragma unroll
  for (int i = 0; i < 4; i++)
#pragma unroll
    for (int j = 0; j < 4; j++) acc[i][j] = (f32x4){0.f, 0.f, 0.f, 0.f};

  uint4 ra0 = *(const uint4*)pa0;
  uint4 ra1 = *(const uint4*)pa1;
  uint4 rb0 = *(const uint4*)pb0;
  uint4 rb1 = *(const uint4*)pb1;

  for (int it = 0; it < iters; ++it) {
    *(uint4*)&As[row * APITCH + off] = ra0;
    *(uint4*)&As[(row + 64) * APITCH + off] = ra1;
    *(uint4*)&Bs[row * APITCH + off] = rb0;
    *(uint4*)&Bs[(row + 64) * APITCH + off] = rb1;
    __syncthreads();
    if (it + 1 < iters) {  // prefetch next k-slab; waitcnt lands at next LDS write
      int d = (it + 1) * 32;
      ra0 = *(const uint4*)(pa0 + d);
      ra1 = *(const uint4*)(pa1 + d);
      rb0 = *(const uint4*)(pb0 + d);
      rb1 = *(const uint4*)(pb1 + d);
    }
    short8 af[4], bfv[4];
#pragma unroll
    for (int f = 0; f < 4; f++)
      af[f] = *(const short8*)&As[(wm + f * 16 + fr) * APITCH + kq];
#pragma unroll
    for (int f = 0; f < 4; f++)
      bfv[f] = *(const short8*)&Bs[(wn + f * 16 + fr) * APITCH + kq];
#pragma unroll
    for (int fm = 0; fm < 4; fm++)
#pragma unroll
      for (int fn = 0; fn < 4; fn++)
        acc[fm][fn] = __builtin_amdgcn_mfma_f32_16x16x32_bf16(af[fm], bfv[fn],
                                                              acc[fm][fn], 0, 0, 0);
    __syncthreads();
  }

  // epilogue: D row = quad*4+reg, col = lane&15
  float* Cp = Cpart + (size_t)blockIdx.z * M * N;
  const int colb = n0 + wn + fr;
  const int rowb = m0 + wm + (lane >> 4) * 4;
#pragma unroll
  for (int fm = 0; fm < 4; fm++)
#pragma unroll
    for (int fn = 0; fn < 4; fn++)
#pragma unroll
      for (int r = 0; r < 4; r++)
        Cp[(size_t)(rowb + fm * 16 + r) * N + (colb + fn * 16)] = acc[fm][fn][r];
}

// ---------------- split-K reduce + bias + relu; optional fp32/bf16 outputs ------
__global__ __launch_bounds__(256) void reduce_bias_relu(
    const float* __restrict__ parts, int nparts, const float* __restrict__ bias,
    float* __restrict__ outf, unsigned short* __restrict__ outb) {
  int i = blockIdx.x * 256 + threadIdx.x;  // total 256*1024
  float s = 0.0f;
  for (int p = 0; p < nparts; ++p) s += parts[(size_t)p * 262144 + i];
  s = fmaxf(s + bias[i & 1023], 0.0f);
  if (outf) outf[i] = s;
  if (outb) outb[i] = f2bf(s);
}

// ---------------- fp32 tiled SGEMM (cls/loc heads), split-K atomic ----------------
__global__ __launch_bounds__(256) void gemm_atomic(
    const float* __restrict__ A, const float* __restrict__ B,
    float* __restrict__ C, int M, int N, int K, int kChunk) {
  __shared__ float Asf[16][68];
  __shared__ float Bsf[16][64];
  const int tid = threadIdx.x;
  const int m0 = blockIdx.y * 64;
  const int n0 = blockIdx.x * 64;
  const int k0 = blockIdx.z * kChunk;
  const int tx = tid & 15;
  const int ty = tid >> 4;
  const int am = tid >> 2;
  const int ak = (tid & 3) << 2;
  const bool vec = ((N & 3) == 0) && (n0 + 64 <= N);

  float acc[4][4];
#pragma unroll
  for (int i = 0; i < 4; i++)
#pragma unroll
    for (int j = 0; j < 4; j++) acc[i][j] = 0.0f;

  for (int kt = k0; kt < k0 + kChunk; kt += 16) {
    float4 av = *(const float4*)(A + (size_t)(m0 + am) * K + (kt + ak));
    Asf[ak + 0][am] = av.x;
    Asf[ak + 1][am] = av.y;
    Asf[ak + 2][am] = av.z;
    Asf[ak + 3][am] = av.w;
    if (vec) {
      *(float4*)(&Bsf[ty][tx << 2]) =
          *(const float4*)(B + (size_t)(kt + ty) * N + (n0 + (tx << 2)));
    } else {
#pragma unroll
      for (int i = 0; i < 4; i++) {
        int e = i * 256 + tid;
        int br = e >> 6, bcc = e & 63;
        int col = n0 + bcc;
        Bsf[br][bcc] = (col < N) ? B[(size_t)(kt + br) * N + col] : 0.0f;
      }
    }
    __syncthreads();
#pragma unroll
    for (int kk = 0; kk < 16; kk++) {
      float4 a = *(const float4*)(&Asf[kk][ty << 2]);
      float4 b = *(const float4*)(&Bsf[kk][tx << 2]);
      acc[0][0] += a.x * b.x; acc[0][1] += a.x * b.y; acc[0][2] += a.x * b.z; acc[0][3] += a.x * b.w;
      acc[1][0] += a.y * b.x; acc[1][1] += a.y * b.y; acc[1][2] += a.y * b.z; acc[1][3] += a.y * b.w;
      acc[2][0] += a.z * b.x; acc[2][1] += a.z * b.y; acc[2][2] += a.z * b.z; acc[2][3] += a.z * b.w;
      acc[3][0] += a.w * b.x; acc[3][1] += a.w * b.y; acc[3][2] += a.w * b.z; acc[3][3] += a.w * b.w;
    }
    __syncthreads();
  }
#pragma unroll
  for (int i = 0; i < 4; i++) {
    int rw = m0 + (ty << 2) + i;
#pragma unroll
    for (int j = 0; j < 4; j++) {
      int col = n0 + (tx << 2) + j;
      if (col < N) atomicAdd(&C[(size_t)rw * N + col], acc[i][j]);
    }
  }
}

// ---------------- decode: softmax, bbox decode, accumulate, argmax -> new roi ----
__global__ __launch_bounds__(128) void decode_kernel(
    const float* __restrict__ logits, const float* __restrict__ bc,
    const float* __restrict__ locr, const float* __restrict__ bl,
    float* __restrict__ roi, float* __restrict__ valid,
    float* __restrict__ pre_b, float* __restrict__ pre_s,
    float st0, float st1, float st2, float st3, int stage) {
  int n = blockIdx.x;
  int t = threadIdx.x;
  __shared__ float red[128];
  __shared__ int redi[128];
  __shared__ float sroi[4];
  __shared__ float boxes[NCLS][4];

  if (t < 4) sroi[t] = roi[n * 4 + t];
  float l = (t < 81) ? (logits[n * 81 + t] + bc[t]) : -INFINITY;
  red[t] = l;
  __syncthreads();
#pragma unroll
  for (int s = 64; s > 0; s >>= 1) {
    if (t < s) red[t] = fmaxf(red[t], red[t + s]);
    __syncthreads();
  }
  float mx = red[0];
  __syncthreads();
  red[t] = (t < 81) ? expf(l - mx) : 0.0f;
  __syncthreads();
#pragma unroll
  for (int s = 64; s > 0; s >>= 1) {
    if (t < s) red[t] += red[t + s];
    __syncthreads();
  }
  float denom = red[0];
  __syncthreads();

  float score = -INFINITY;
  if (t < NCLS) {
    float lj = logits[n * 81 + t + 1] + bc[t + 1];
    score = expf(lj - mx) / denom;
    const float* lp = locr + (size_t)n * 324 + (t + 1) * 4;
    const float* bp = bl + (t + 1) * 4;
    float dy = (lp[0] + bp[0]) * st0;
    float dx = (lp[1] + bp[1]) * st1;
    float dh = (lp[2] + bp[2]) * st2;
    float dw = (lp[3] + bp[3]) * st3;
    float h_ = sroi[2] - sroi[0];
    float w_ = sroi[3] - sroi[1];
    float cy = sroi[0] + h_ * 0.5f;
    float cx = sroi[1] + w_ * 0.5f;
    float ny = dy * h_ + cy;
    float nx = dx * w_ + cx;
    float nh = expf(dh) * h_;
    float nw = expf(dw) * w_;
    float b0 = ny - nh * 0.5f;
    float b1v = nx - nw * 0.5f;
    float b2v = ny + nh * 0.5f;
    float b3v = nx + nw * 0.5f;
    int o = (n * NCLS + t) * 4;
    pre_b[o + 0] += b0;
    pre_b[o + 1] += b1v;
    pre_b[o + 2] += b2v;
    pre_b[o + 3] += b3v;
    pre_s[n * NCLS + t] += score;
    boxes[t][0] = b0;
    boxes[t][1] = b1v;
    boxes[t][2] = b2v;
    boxes[t][3] = b3v;
  }
  red[t] = score;
  redi[t] = t;
  __syncthreads();
  for (int s = 64; s > 0; s >>= 1) {
    if (t < s) {
      float o2 = red[t + s];
      int oi = redi[t + s];
      if (o2 > red[t] || (o2 == red[t] && oi < redi[t])) {
        red[t] = o2;
        redi[t] = oi;
      }
    }
    __syncthreads();
  }
  if (t == 0) {
    int best = redi[0];
    float ry1 = fminf(fmaxf(boxes[best][0], 0.0f), 1024.0f);
    float rx1 = fminf(fmaxf(boxes[best][1], 0.0f), 1024.0f);
    float ry2 = fminf(fmaxf(boxes[best][2], 0.0f), 1024.0f);
    float rx2 = fminf(fmaxf(boxes[best][3], 0.0f), 1024.0f);
    roi[n * 4 + 0] = ry1;
    roi[n * 4 + 1] = rx1;
    roi[n * 4 + 2] = ry2;
    roi[n * 4 + 3] = rx2;
    if (stage < 2) {
      float hh = ry2 - ry1, ww = rx2 - rx1;
      if (!(hh >= 16.0f && ww >= 16.0f)) valid[n] = 0.0f;
    }
  }
}

// ---------------- finalize: apply valid mask and /3, write output ----------------
__global__ __launch_bounds__(256) void finalize_kernel(
    const float* __restrict__ pre_b, const float* __restrict__ pre_s,
    const float* __restrict__ valid, float* __restrict__ out) {
  int i = blockIdx.x * 256 + threadIdx.x;
  if (i < NROI * NCLS * 4) {
    int n = i / (NCLS * 4);
    out[i] = pre_b[i] * valid[n] * (1.0f / 3.0f);
  } else if (i < NROI * NCLS * 4 + NROI * NCLS) {
    int j = i - NROI * NCLS * 4;
    int n = j / NCLS;
    out[i] = pre_s[j] * valid[n] * (1.0f / 3.0f);
  }
}

extern "C" void kernel_launch(void* const* d_in, const int* in_sizes, int n_in,
                              void* d_out, int out_size, void* d_ws, size_t ws_size,
                              hipStream_t stream) {
  const float* P0 = (const float*)d_in[0];
  const float* P1 = (const float*)d_in[1];
  const float* P2 = (const float*)d_in[2];
  const float* P3 = (const float*)d_in[3];
  const float* rois = (const float*)d_in[4];
  float* out = (float*)d_out;
  float* ws = (float*)d_ws;

  // ---- ws layout ----
  float* roi   = ws;                      // 1024
  float* valid = roi + 1024;              // 256
  float* pre_b = valid + 256;             // 81920
  float* pre_s = pre_b + 81920;           // 20480
  float* h2    = pre_s + 20480;           // 262144
  float* logit = h2 + 262144;             // 20736
  float* loc   = logit + 20736;           // 82944
  float* part1 = loc + 82944;             // 14 * 262144
  float* part2 = part1 + 14 * 262144;     // 8 * 262144
  unsigned short* pooledb = (unsigned short*)(part2 + 8 * 262144);  // 256*12544
  unsigned short* Wt1 = pooledb + 256 * 12544;                      // 1024*12544
  unsigned short* Wt2 = Wt1 + 1024 * 12544;                         // 1024*1024
  unsigned short* h1b = Wt2 + 1024 * 1024;                          // 256*1024
  // total ~= 60 MB

  init_kernel<<<4, 256, 0, stream>>>(rois, roi, valid);
  hipMemsetAsync(pre_b, 0, (size_t)(81920 + 20480) * sizeof(float), stream);

  const float stds[3][4] = {
      {0.1f, 0.1f, 0.2f, 0.2f},
      {0.05f, 0.05f, 0.1f, 0.1f},
      {1.0f / 30.0f, 1.0f / 30.0f, 1.0f / 15.0f, 1.0f / 15.0f}};

  for (int s = 0; s < 3; s++) {
    const float* W1 = (const float*)d_in[5 + s * 8 + 0];
    const float* b1 = (const float*)d_in[5 + s * 8 + 1];
    const float* W2 = (const float*)d_in[5 + s * 8 + 2];
    const float* b2 = (const float*)d_in[5 + s * 8 + 3];
    const float* Wc = (const float*)d_in[5 + s * 8 + 4];
    const float* bc = (const float*)d_in[5 + s * 8 + 5];
    const float* Wl = (const float*)d_in[5 + s * 8 + 6];
    const float* bl = (const float*)d_in[5 + s * 8 + 7];

    // W1 (12544,1024) -> Wt1 (1024,12544) bf16 ; W2 (1024,1024) -> Wt2
    transpose_bf16<<<dim3(392, 32), 256, 0, stream>>>(W1, Wt1, 12544, 1024);
    transpose_bf16<<<dim3(32, 32), 256, 0, stream>>>(W2, Wt2, 1024, 1024);

    pool_kernel<<<12544, 256, 0, stream>>>(P0, P1, P2, P3, roi, pooledb);

    // FC1: (256x12544)@(12544x1024) -> part1[14], iters=392/14=28
    gemm_bf16<<<dim3(8, 2, 14), 256, 0, stream>>>(pooledb, Wt1, part1, 256, 1024, 12544, 28);
    reduce_bias_relu<<<1024, 256, 0, stream>>>(part1, 14, b1, nullptr, h1b);

    // FC2: (256x1024)@(1024x1024) -> part2[8], iters=32/8=4
    gemm_bf16<<<dim3(8, 2, 8), 256, 0, stream>>>(h1b, Wt2, part2, 256, 1024, 1024, 4);
    reduce_bias_relu<<<1024, 256, 0, stream>>>(part2, 8, b2, h2, nullptr);

    // cls/loc heads: fp32 (small); zero accumulators (logit,loc contiguous)
    hipMemsetAsync(logit, 0, (size_t)(20736 + 82944) * sizeof(float), stream);
    gemm_atomic<<<dim3(2, 4, 4), 256, 0, stream>>>(h2, Wc, logit, 256, 81, 1024, 256);
    gemm_atomic<<<dim3(6, 4, 4), 256, 0, stream>>>(h2, Wl, loc, 256, 324, 1024, 256);

    decode_kernel<<<256, 128, 0, stream>>>(logit, bc, loc, bl, roi, valid, pre_b, pre_s,
                                           stds[s][0], stds[s][1], stds[s][2], stds[s][3], s);
  }

  finalize_kernel<<<400, 256, 0, stream>>>(pre_b, pre_s, valid, out);
}

// Round 3
// 505.722 us; speedup vs baseline: 2.2678x; 1.4495x over previous
//
#include <hip/hip_runtime.h>
#include <math.h>

// Mask R-CNN cascade head.
// Features pre-transposed to [H][W][C] bf16 once per launch -> coalesced pool reads.
// K-order for FC1 is position-major (k = p*256 + c) to match pool's coalesced writes.
// FC1/FC2/heads all bf16 MFMA (16x16x32), fp32 accumulate. Heads fused (N=512 padded).

#define NROI 256
#define NCLS 80
#define APITCH 40  // 32 k + 8 pad (bf16 elems); 80B row pitch keeps 16B alignment

typedef __attribute__((ext_vector_type(8))) short short8;
typedef __attribute__((ext_vector_type(4))) float f32x4;

__device__ __forceinline__ unsigned short f2bf(float f) {
  unsigned u = __builtin_bit_cast(unsigned, f);
  unsigned r = (u + 0x7FFFu + ((u >> 16) & 1u)) >> 16;  // RNE
  return (unsigned short)r;
}
__device__ __forceinline__ float bf2f(unsigned short u) {
  return __builtin_bit_cast(float, (unsigned)u << 16);
}

// ---------------- init: copy rois into ws, valid=1 ----------------
__global__ __launch_bounds__(256) void init_kernel(const float* __restrict__ rois,
                                                   float* __restrict__ roi,
                                                   float* __restrict__ valid) {
  int i = blockIdx.x * 256 + threadIdx.x;
  if (i < NROI * 4) roi[i] = rois[i];
  if (i < NROI) valid[i] = 1.0f;
}

// ---------------- transpose + fp32->bf16: W (K,N) -> Wt (N,K) ----------------
// Also used for feature maps: P (C, HW) -> Pb (HW, C) with K=C, N=HW.
__global__ __launch_bounds__(256) void transpose_bf16(const float* __restrict__ W,
                                                      unsigned short* __restrict__ Wt,
                                                      int K, int N) {
  __shared__ unsigned short tile[32][33];
  int t = threadIdx.x;
  int k0 = blockIdx.x * 32;
  int n0 = blockIdx.y * 32;
  int r = t >> 3;
  int c4 = (t & 7) * 4;
  float4 v = *(const float4*)(W + (size_t)(k0 + r) * N + n0 + c4);
  tile[r][c4 + 0] = f2bf(v.x);
  tile[r][c4 + 1] = f2bf(v.y);
  tile[r][c4 + 2] = f2bf(v.z);
  tile[r][c4 + 3] = f2bf(v.w);
  __syncthreads();
  struct __attribute__((aligned(8))) US4 { unsigned short a, b, c, d; } o;
  o.a = tile[c4 + 0][r];
  o.b = tile[c4 + 1][r];
  o.c = tile[c4 + 2][r];
  o.d = tile[c4 + 3][r];
  *(US4*)(Wt + (size_t)(n0 + r) * K + k0 + c4) = o;
}

// ---------------- W1 transpose with K-permutation ----------------
// W1 is (12544, 1024) with k_src = c*49 + p. Dest Wt1 (1024, 12544) with
// kd = p*256 + c. Wt1[n][p*256+c] = W1[c*49+p][n].
__global__ __launch_bounds__(256) void transpose_w1(const float* __restrict__ W,
                                                    unsigned short* __restrict__ Wt) {
  __shared__ unsigned short tile[32][33];
  int t = threadIdx.x;
  int kd0 = blockIdx.x * 32;       // 32-aligned -> single p per tile
  int n0 = blockIdx.y * 32;
  int p = kd0 >> 8;
  int c0 = kd0 & 255;
  int r = t >> 3;
  int c4 = (t & 7) * 4;
  int k_src = (c0 + r) * 49 + p;
  float4 v = *(const float4*)(W + (size_t)k_src * 1024 + n0 + c4);
  tile[r][c4 + 0] = f2bf(v.x);
  tile[r][c4 + 1] = f2bf(v.y);
  tile[r][c4 + 2] = f2bf(v.z);
  tile[r][c4 + 3] = f2bf(v.w);
  __syncthreads();
  struct __attribute__((aligned(8))) US4 { unsigned short a, b, c, d; } o;
  o.a = tile[c4 + 0][r];
  o.b = tile[c4 + 1][r];
  o.c = tile[c4 + 2][r];
  o.d = tile[c4 + 3][r];
  *(US4*)(Wt + (size_t)(n0 + r) * 12544 + kd0 + c4) = o;
}

// ---------------- fused head weight transpose: [Wc | Wl | pad] -> (512, 1024) ----
__global__ __launch_bounds__(256) void head_transpose(const float* __restrict__ Wc,
                                                      const float* __restrict__ Wl,
                                                      unsigned short* __restrict__ Wt) {
  __shared__ unsigned short tile[32][33];
  int t = threadIdx.x;
  int k0 = blockIdx.x * 32;   // K = 1024
  int n0 = blockIdx.y * 32;   // N = 512 (81 cls + 324 loc + pad)
  int r = t >> 3;
  int c4 = (t & 7) * 4;
#pragma unroll
  for (int j = 0; j < 4; j++) {
    int nn = n0 + c4 + j;
    float v = 0.0f;
    if (nn < 81) v = Wc[(size_t)(k0 + r) * 81 + nn];
    else if (nn < 405) v = Wl[(size_t)(k0 + r) * 324 + (nn - 81)];
    tile[r][c4 + j] = f2bf(v);
  }
  __syncthreads();
  struct __attribute__((aligned(8))) US4 { unsigned short a, b, c, d; } o;
  o.a = tile[c4 + 0][r];
  o.b = tile[c4 + 1][r];
  o.c = tile[c4 + 2][r];
  o.d = tile[c4 + 3][r];
  *(US4*)(Wt + (size_t)(n0 + r) * 1024 + k0 + c4) = o;
}

// ---------------- ROI align pool v2: [H][W][C] bf16 features ----------------
// grid (13, 256): blockIdx.y = roi, wave = position p = bx*4 + wave.
// lane handles 4 channels; all coords wave-uniform; corner reads 512B/wave coalesced.
// Output pooled[n][p*256 + c] bf16 (position-major K).
__global__ __launch_bounds__(256) void pool_kernel2(
    const unsigned short* __restrict__ Pb0, const unsigned short* __restrict__ Pb1,
    const unsigned short* __restrict__ Pb2, const unsigned short* __restrict__ Pb3,
    const float* __restrict__ roi, unsigned short* __restrict__ pooled) {
  int t = threadIdx.x;
  int n = blockIdx.y;
  int p = blockIdx.x * 4 + (t >> 6);
  if (p >= 49) return;
  int lane = t & 63;
  int c4 = lane * 4;
  int py = p / 7, px = p % 7;

  float r0 = roi[n * 4 + 0];
  float r1 = roi[n * 4 + 1];
  float r2 = roi[n * 4 + 2];
  float r3 = roi[n * 4 + 3];

  float area = (r2 - r0 + 1.0f) * (r3 - r1 + 1.0f);
  float lf = floorf(4.0f + log2f(sqrtf(area) / 224.0f));
  lf = fminf(fmaxf(lf, 2.0f), 5.0f);
  int lvl = (int)lf - 2;

  float scale;
  int H;
  const unsigned short* fb;
  if (lvl == 0)      { scale = 0.25f;    H = 256; fb = Pb0; }
  else if (lvl == 1) { scale = 0.125f;   H = 128; fb = Pb1; }
  else if (lvl == 2) { scale = 0.0625f;  H = 64;  fb = Pb2; }
  else               { scale = 0.03125f; H = 32;  fb = Pb3; }
  int W = H;

  float y1 = r0 * scale;
  float x1 = r1 * scale;
  float rh = fmaxf(r2 * scale - y1, 1.0f);
  float rw = fmaxf(r3 * scale - x1, 1.0f);
  float bh = rh * (1.0f / 7.0f);
  float bw = rw * (1.0f / 7.0f);

  float a0 = 0.f, a1 = 0.f, a2 = 0.f, a3 = 0.f;
#pragma unroll
  for (int ry = 0; ry < 2; ry++) {
    float yy = y1 + ((float)py + ((float)ry + 0.5f) * 0.5f) * bh;
    bool vy = (yy > -1.0f) && (yy < (float)H);
    float ycl = fminf(fmaxf(yy, 0.0f), (float)(H - 1));
    float y0f = floorf(ycl);
    float ly = ycl - y0f;
    int y0i = (int)y0f;
    int y1i = min(y0i + 1, H - 1);
#pragma unroll
    for (int rx = 0; rx < 2; rx++) {
      float xx = x1 + ((float)px + ((float)rx + 0.5f) * 0.5f) * bw;
      bool vx = (xx > -1.0f) && (xx < (float)W);
      float xcl = fminf(fmaxf(xx, 0.0f), (float)(W - 1));
      float x0f = floorf(xcl);
      float lx = xcl - x0f;
      int x0i = (int)x0f;
      int x1i = min(x0i + 1, W - 1);
      float w00 = (1.f - ly) * (1.f - lx);
      float w01 = (1.f - ly) * lx;
      float w10 = ly * (1.f - lx);
      float w11 = ly * lx;
      if (!(vy && vx)) { w00 = w01 = w10 = w11 = 0.f; }
      ushort4 f00 = *(const ushort4*)(fb + ((size_t)(y0i * W + x0i) * 256 + c4));
      ushort4 f01 = *(const ushort4*)(fb + ((size_t)(y0i * W + x1i) * 256 + c4));
      ushort4 f10 = *(const ushort4*)(fb + ((size_t)(y1i * W + x0i) * 256 + c4));
      ushort4 f11 = *(const ushort4*)(fb + ((size_t)(y1i * W + x1i) * 256 + c4));
      a0 += bf2f(f00.x) * w00 + bf2f(f01.x) * w01 + bf2f(f10.x) * w10 + bf2f(f11.x) * w11;
      a1 += bf2f(f00.y) * w00 + bf2f(f01.y) * w01 + bf2f(f10.y) * w10 + bf2f(f11.y) * w11;
      a2 += bf2f(f00.z) * w00 + bf2f(f01.z) * w01 + bf2f(f10.z) * w10 + bf2f(f11.z) * w11;
      a3 += bf2f(f00.w) * w00 + bf2f(f01.w) * w01 + bf2f(f10.w) * w10 + bf2f(f11.w) * w11;
    }
  }
  ushort4 o;
  o.x = f2bf(a0 * 0.25f);
  o.y = f2bf(a1 * 0.25f);
  o.z = f2bf(a2 * 0.25f);
  o.w = f2bf(a3 * 0.25f);
  *(ushort4*)(pooled + (size_t)n * 12544 + p * 256 + c4) = o;
}

// ---------------- bf16 MFMA GEMM: C = A(MxK) @ Bt(NxK)^T, split-K partials ---------
__global__ __launch_bounds__(256) void gemm_bf16(
    const unsigned short* __restrict__ A, const unsigned short* __restrict__ B,
    float* __restrict__ Cpart, int M, int N, int K, int iters) {
  __shared__ unsigned short As[128 * APITCH];
  __shared__ unsigned short Bs[128 * APITCH];
  const int t = threadIdx.x;
  const int n0 = blockIdx.x * 128;
  const int m0 = blockIdx.y * 128;
  const size_t kt0 = (size_t)blockIdx.z * iters * 32;

  const int row = t >> 2;
  const int off = (t & 3) * 8;
  const unsigned short* pa0 = A + (size_t)(m0 + row) * K + kt0 + off;
  const unsigned short* pa1 = pa0 + (size_t)64 * K;
  const unsigned short* pb0 = B + (size_t)(n0 + row) * K + kt0 + off;
  const unsigned short* pb1 = pb0 + (size_t)64 * K;

  const int lane = t & 63;
  const int wave = t >> 6;
  const int wm = (wave >> 1) * 64;
  const int wn = (wave & 1) * 64;
  const int fr = lane & 15;
  const int kq = (lane >> 4) * 8;

  f32x4 acc[4][4];
#pragma unroll
  for (int i = 0; i < 4; i++)
#pragma unroll
    for (int j = 0; j < 4; j++) acc[i][j] = (f32x4){0.f, 0.f, 0.f, 0.f};

  uint4 ra0 = *(const uint4*)pa0;
  uint4 ra1 = *(const uint4*)pa1;
  uint4 rb0 = *(const uint4*)pb0;
  uint4 rb1 = *(const uint4*)pb1;

  for (int it = 0; it < iters; ++it) {
    *(uint4*)&As[row * APITCH + off] = ra0;
    *(uint4*)&As[(row + 64) * APITCH + off] = ra1;
    *(uint4*)&Bs[row * APITCH + off] = rb0;
    *(uint4*)&Bs[(row + 64) * APITCH + off] = rb1;
    __syncthreads();
    if (it + 1 < iters) {
      int d = (it + 1) * 32;
      ra0 = *(const uint4*)(pa0 + d);
      ra1 = *(const uint4*)(pa1 + d);
      rb0 = *(const uint4*)(pb0 + d);
      rb1 = *(const uint4*)(pb1 + d);
    }
    short8 af[4], bfv[4];
#pragma unroll
    for (int f = 0; f < 4; f++)
      af[f] = *(const short8*)&As[(wm + f * 16 + fr) * APITCH + kq];
#pragma unroll
    for (int f = 0; f < 4; f++)
      bfv[f] = *(const short8*)&Bs[(wn + f * 16 + fr) * APITCH + kq];
#pragma unroll
    for (int fm = 0; fm < 4; fm++)
#pragma unroll
      for (int fn = 0; fn < 4; fn++)
        acc[fm][fn] = __builtin_amdgcn_mfma_f32_16x16x32_bf16(af[fm], bfv[fn],
                                                              acc[fm][fn], 0, 0, 0);
    __syncthreads();
  }

  float* Cp = Cpart + (size_t)blockIdx.z * M * N;
  const int colb = n0 + wn + fr;
  const int rowb = m0 + wm + (lane >> 4) * 4;
#pragma unroll
  for (int fm = 0; fm < 4; fm++)
#pragma unroll
    for (int fn = 0; fn < 4; fn++)
#pragma unroll
      for (int r = 0; r < 4; r++)
        Cp[(size_t)(rowb + fm * 16 + r) * N + (colb + fn * 16)] = acc[fm][fn][r];
}

// ---------------- split-K reduce + bias + relu -> bf16 ----------------
__global__ __launch_bounds__(256) void reduce_bias_relu(
    const float* __restrict__ parts, int nparts, const float* __restrict__ bias,
    unsigned short* __restrict__ outb) {
  int i = blockIdx.x * 256 + threadIdx.x;  // total 256*1024
  float s = 0.0f;
  for (int p = 0; p < nparts; ++p) s += parts[(size_t)p * 262144 + i];
  s = fmaxf(s + bias[i & 1023], 0.0f);
  outb[i] = f2bf(s);
}

// ---------------- decode: softmax, bbox decode, accumulate, argmax -> new roi ----
// Heads output is 4 split-K partials of a (256 x 512) buffer: cols 0..80 logits,
// cols 81..404 loc (index (cls+1)*4+j at col 81+(cls+1)*4+j... using raw loc col
// layout: col 81 + cidx*4 + j for cidx in 0..80).
__global__ __launch_bounds__(128) void decode_kernel(
    const float* __restrict__ headp, const float* __restrict__ bc,
    const float* __restrict__ bl,
    float* __restrict__ roi, float* __restrict__ valid,
    float* __restrict__ pre_b, float* __restrict__ pre_s,
    float st0, float st1, float st2, float st3, int stage) {
  int n = blockIdx.x;
  int t = threadIdx.x;
  __shared__ float red[128];
  __shared__ int redi[128];
  __shared__ float sroi[4];
  __shared__ float boxes[NCLS][4];

  if (t < 4) sroi[t] = roi[n * 4 + t];
  float l = -INFINITY;
  if (t < 81) {
    float s = 0.f;
#pragma unroll
    for (int z = 0; z < 4; z++) s += headp[(size_t)z * 131072 + n * 512 + t];
    l = s + bc[t];
  }
  red[t] = l;
  __syncthreads();
#pragma unroll
  for (int s = 64; s > 0; s >>= 1) {
    if (t < s) red[t] = fmaxf(red[t], red[t + s]);
    __syncthreads();
  }
  float mx = red[0];
  __syncthreads();
  red[t] = (t < 81) ? expf(l - mx) : 0.0f;
  __syncthreads();
#pragma unroll
  for (int s = 64; s > 0; s >>= 1) {
    if (t < s) red[t] += red[t + s];
    __syncthreads();
  }
  float denom = red[0];
  __syncthreads();

  float score = -INFINITY;
  if (t < NCLS) {
    float lj = 0.f;
#pragma unroll
    for (int z = 0; z < 4; z++) lj += headp[(size_t)z * 131072 + n * 512 + (t + 1)];
    lj += bc[t + 1];
    score = expf(lj - mx) / denom;
    float lp[4];
#pragma unroll
    for (int j = 0; j < 4; j++) {
      float s = 0.f;
#pragma unroll
      for (int z = 0; z < 4; z++)
        s += headp[(size_t)z * 131072 + n * 512 + 81 + (t + 1) * 4 + j];
      lp[j] = s + bl[(t + 1) * 4 + j];
    }
    float dy = lp[0] * st0;
    float dx = lp[1] * st1;
    float dh = lp[2] * st2;
    float dw = lp[3] * st3;
    float h_ = sroi[2] - sroi[0];
    float w_ = sroi[3] - sroi[1];
    float cy = sroi[0] + h_ * 0.5f;
    float cx = sroi[1] + w_ * 0.5f;
    float ny = dy * h_ + cy;
    float nx = dx * w_ + cx;
    float nh = expf(dh) * h_;
    float nw = expf(dw) * w_;
    float b0 = ny - nh * 0.5f;
    float b1v = nx - nw * 0.5f;
    float b2v = ny + nh * 0.5f;
    float b3v = nx + nw * 0.5f;
    int o = (n * NCLS + t) * 4;
    pre_b[o + 0] += b0;
    pre_b[o + 1] += b1v;
    pre_b[o + 2] += b2v;
    pre_b[o + 3] += b3v;
    pre_s[n * NCLS + t] += score;
    boxes[t][0] = b0;
    boxes[t][1] = b1v;
    boxes[t][2] = b2v;
    boxes[t][3] = b3v;
  }
  red[t] = score;
  redi[t] = t;
  __syncthreads();
  for (int s = 64; s > 0; s >>= 1) {
    if (t < s) {
      float o2 = red[t + s];
      int oi = redi[t + s];
      if (o2 > red[t] || (o2 == red[t] && oi < redi[t])) {
        red[t] = o2;
        redi[t] = oi;
      }
    }
    __syncthreads();
  }
  if (t == 0) {
    int best = redi[0];
    float ry1 = fminf(fmaxf(boxes[best][0], 0.0f), 1024.0f);
    float rx1 = fminf(fmaxf(boxes[best][1], 0.0f), 1024.0f);
    float ry2 = fminf(fmaxf(boxes[best][2], 0.0f), 1024.0f);
    float rx2 = fminf(fmaxf(boxes[best][3], 0.0f), 1024.0f);
    roi[n * 4 + 0] = ry1;
    roi[n * 4 + 1] = rx1;
    roi[n * 4 + 2] = ry2;
    roi[n * 4 + 3] = rx2;
    if (stage < 2) {
      float hh = ry2 - ry1, ww = rx2 - rx1;
      if (!(hh >= 16.0f && ww >= 16.0f)) valid[n] = 0.0f;
    }
  }
}

// ---------------- finalize ----------------
__global__ __launch_bounds__(256) void finalize_kernel(
    const float* __restrict__ pre_b, const float* __restrict__ pre_s,
    const float* __restrict__ valid, float* __restrict__ out) {
  int i = blockIdx.x * 256 + threadIdx.x;
  if (i < NROI * NCLS * 4) {
    int n = i / (NCLS * 4);
    out[i] = pre_b[i] * valid[n] * (1.0f / 3.0f);
  } else if (i < NROI * NCLS * 4 + NROI * NCLS) {
    int j = i - NROI * NCLS * 4;
    int n = j / NCLS;
    out[i] = pre_s[j] * valid[n] * (1.0f / 3.0f);
  }
}

extern "C" void kernel_launch(void* const* d_in, const int* in_sizes, int n_in,
                              void* d_out, int out_size, void* d_ws, size_t ws_size,
                              hipStream_t stream) {
  const float* P0 = (const float*)d_in[0];
  const float* P1 = (const float*)d_in[1];
  const float* P2 = (const float*)d_in[2];
  const float* P3 = (const float*)d_in[3];
  const float* rois = (const float*)d_in[4];
  float* out = (float*)d_out;
  float* ws = (float*)d_ws;

  // ---- ws layout (fp32 region first, then bf16 region) ----
  float* roi   = ws;                      // 1024
  float* valid = roi + 1024;              // 256
  float* pre_b = valid + 256;             // 81920
  float* pre_s = pre_b + 81920;           // 20480
  float* part1 = pre_s + 20480;           // 14 * 262144
  float* part2 = part1 + 14 * 262144;     // 8 * 262144
  float* parth = part2 + 8 * 262144;      // 4 * 131072
  unsigned short* pooledb = (unsigned short*)(parth + 4 * 131072);  // 256*12544
  unsigned short* Wt1 = pooledb + (size_t)256 * 12544;              // 1024*12544
  unsigned short* Wt2 = Wt1 + (size_t)1024 * 12544;                 // 1024*1024
  unsigned short* Wth = Wt2 + (size_t)1024 * 1024;                  // 512*1024
  unsigned short* h1b = Wth + (size_t)512 * 1024;                   // 256*1024
  unsigned short* h2b = h1b + (size_t)256 * 1024;                   // 256*1024
  unsigned short* Pb0 = h2b + (size_t)256 * 1024;                   // 65536*256
  unsigned short* Pb1 = Pb0 + (size_t)65536 * 256;                  // 16384*256
  unsigned short* Pb2 = Pb1 + (size_t)16384 * 256;                  // 4096*256
  unsigned short* Pb3 = Pb2 + (size_t)4096 * 256;                   // 1024*256
  // total ~= 106 MB

  init_kernel<<<4, 256, 0, stream>>>(rois, roi, valid);
  hipMemsetAsync(pre_b, 0, (size_t)(81920 + 20480) * sizeof(float), stream);

  // Feature transpose: P[l] (C=256, HW) fp32 -> Pb[l] (HW, 256) bf16, once.
  transpose_bf16<<<dim3(8, 2048), 256, 0, stream>>>(P0, Pb0, 256, 65536);
  transpose_bf16<<<dim3(8, 512),  256, 0, stream>>>(P1, Pb1, 256, 16384);
  transpose_bf16<<<dim3(8, 128),  256, 0, stream>>>(P2, Pb2, 256, 4096);
  transpose_bf16<<<dim3(8, 32),   256, 0, stream>>>(P3, Pb3, 256, 1024);

  const float stds[3][4] = {
      {0.1f, 0.1f, 0.2f, 0.2f},
      {0.05f, 0.05f, 0.1f, 0.1f},
      {1.0f / 30.0f, 1.0f / 30.0f, 1.0f / 15.0f, 1.0f / 15.0f}};

  for (int s = 0; s < 3; s++) {
    const float* W1 = (const float*)d_in[5 + s * 8 + 0];
    const float* b1 = (const float*)d_in[5 + s * 8 + 1];
    const float* W2 = (const float*)d_in[5 + s * 8 + 2];
    const float* b2 = (const float*)d_in[5 + s * 8 + 3];
    const float* Wc = (const float*)d_in[5 + s * 8 + 4];
    const float* bc = (const float*)d_in[5 + s * 8 + 5];
    const float* Wl = (const float*)d_in[5 + s * 8 + 6];
    const float* bl = (const float*)d_in[5 + s * 8 + 7];

    transpose_w1<<<dim3(392, 32), 256, 0, stream>>>(W1, Wt1);
    transpose_bf16<<<dim3(32, 32), 256, 0, stream>>>(W2, Wt2, 1024, 1024);
    head_transpose<<<dim3(32, 16), 256, 0, stream>>>(Wc, Wl, Wth);

    pool_kernel2<<<dim3(13, 256), 256, 0, stream>>>(Pb0, Pb1, Pb2, Pb3, roi, pooledb);

    // FC1: (256x12544)@(12544x1024)^T -> part1[14], iters = 392/14 = 28
    gemm_bf16<<<dim3(8, 2, 14), 256, 0, stream>>>(pooledb, Wt1, part1, 256, 1024, 12544, 28);
    reduce_bias_relu<<<1024, 256, 0, stream>>>(part1, 14, b1, h1b);

    // FC2: (256x1024)@(1024x1024)^T -> part2[8], iters = 4
    gemm_bf16<<<dim3(8, 2, 8), 256, 0, stream>>>(h1b, Wt2, part2, 256, 1024, 1024, 4);
    reduce_bias_relu<<<1024, 256, 0, stream>>>(part2, 8, b2, h2b);

    // fused heads: (256x1024)@(1024x512)^T -> parth[4], iters = 8
    gemm_bf16<<<dim3(4, 2, 4), 256, 0, stream>>>(h2b, Wth, parth, 256, 512, 1024, 8);

    decode_kernel<<<256, 128, 0, stream>>>(parth, bc, bl, roi, valid, pre_b, pre_s,
                                           stds[s][0], stds[s][1], stds[s][2], stds[s][3], s);
  }

  finalize_kernel<<<400, 256, 0, stream>>>(pre_b, pre_s, valid, out);
}